// Round 1
// baseline (272.081 us; speedup 1.0000x reference)
//
#include <hip/hip_runtime.h>
#include <math.h>

// Problem constants (from reference): B*T = 32768 rows, C=1, V=256, K=512.
#define NV 256        // vector dim
#define NK 512        // codebook size
#define RPB 16        // rows per block in main kernel

typedef unsigned long long ull;

// Monotone float -> uint mapping: preserves ordering (no NaNs expected).
__device__ __forceinline__ unsigned int fkey(float f) {
    unsigned int u = __float_as_uint(f);
    return (u & 0x80000000u) ? ~u : (u | 0x80000000u);
}

// Kernel 0: per-code squared norm + zero histogram.
__global__ __launch_bounds__(256) void vq_prep(const float* __restrict__ emb,
                                               float* __restrict__ esq,
                                               int* __restrict__ hist) {
    int k = blockIdx.x * 256 + threadIdx.x;
    if (k < NK) {
        const float4* e = (const float4*)(emb + (size_t)k * NV);
        float s = 0.0f;
#pragma unroll 8
        for (int v = 0; v < NV / 4; ++v) {
            float4 a = e[v];
            s += a.x * a.x + a.y * a.y + a.z * a.z + a.w * a.w;
        }
        esq[k] = s;
        hist[k] = 0;
    }
}

// Kernel 1: per-row nearest-code search + outputs.
// Block = 256 threads, handles RPB=16 consecutive rows. Thread t owns codes
// {t, t+256} for all 16 rows.
__global__ __launch_bounds__(256) void vq_main(const float* __restrict__ x,
                                               const float* __restrict__ emb,
                                               const float* __restrict__ esq,
                                               int* __restrict__ hist,
                                               float* __restrict__ out0,
                                               float* __restrict__ out1,
                                               float* __restrict__ out2) {
    __shared__ float xs[RPB][NV];          // 16 KB
    __shared__ ull   red[RPB][256];        // 32 KB (reused as float for sums)
    __shared__ int   idxs[RPB];

    const int t = threadIdx.x;
    const size_t n0 = (size_t)blockIdx.x * RPB;

    // --- stage 16 rows of x into LDS (coalesced float4) ---
    {
        const float4* xg = (const float4*)(x + n0 * NV);
        float4* xs4 = (float4*)&xs[0][0];
#pragma unroll
        for (int i = 0; i < (RPB * NV / 4) / 256; ++i)  // 4 iters
            xs4[i * 256 + t] = xg[i * 256 + t];
    }
    __syncthreads();

    // --- cross products: thread t computes dot(x_r, e_t) and dot(x_r, e_{t+256}) ---
    float acc0[RPB], acc1[RPB];
#pragma unroll
    for (int r = 0; r < RPB; ++r) { acc0[r] = 0.0f; acc1[r] = 0.0f; }

    const float4* e0 = (const float4*)(emb + (size_t)t * NV);
    const float4* e1 = (const float4*)(emb + (size_t)(t + 256) * NV);

    for (int v = 0; v < NV / 4; ++v) {
        float4 ea = e0[v];
        float4 eb = e1[v];
#pragma unroll
        for (int r = 0; r < RPB; ++r) {
            float4 xv = ((const float4*)xs[r])[v];  // LDS broadcast
            acc0[r] += ea.x * xv.x + ea.y * xv.y + ea.z * xv.z + ea.w * xv.w;
            acc1[r] += eb.x * xv.x + eb.y * xv.y + eb.z * xv.z + eb.w * xv.w;
        }
    }

    // --- per-row argmin over 512 codes (scores: esq - 2*cross; x_sq constant) ---
    const float esq0 = esq[t];
    const float esq1 = esq[t + 256];
#pragma unroll
    for (int r = 0; r < RPB; ++r) {
        float d0 = fmaf(-2.0f, acc0[r], esq0);
        float d1 = fmaf(-2.0f, acc1[r], esq1);
        ull k0 = ((ull)fkey(d0) << 32) | (unsigned int)t;
        ull k1 = ((ull)fkey(d1) << 32) | (unsigned int)(t + 256);
        red[r][t] = k0 < k1 ? k0 : k1;   // tie -> smaller k (k0 < k1 always in index)
    }
    __syncthreads();
    for (int s = 128; s >= 1; s >>= 1) {
        if (t < s) {
#pragma unroll
            for (int r = 0; r < RPB; ++r) {
                ull a = red[r][t], b = red[r][t + s];
                red[r][t] = b < a ? b : a;
            }
        }
        __syncthreads();
    }
    if (t < RPB) {
        int idx = (int)(red[t][0] & 0xffffffffu);
        idxs[t] = idx;
        atomicAdd(&hist[idx], 1);
    }
    __syncthreads();

    // --- gather + straight-through out0, and diff^2 for the loss sums ---
    float dsq[RPB];
#pragma unroll
    for (int r = 0; r < RPB; ++r) {
        int idx = idxs[r];
        float ev = emb[(size_t)idx * NV + t];   // coalesced per row
        float xv = xs[r][t];
        out0[(n0 + r) * NV + t] = (ev - xv) + xv;  // match fp32 op order of ref
        float diff = xv - ev;
        dsq[r] = diff * diff;
    }
    __syncthreads();  // done with red as ull

    float (*redf)[256] = (float (*)[256])&red[0][0];
#pragma unroll
    for (int r = 0; r < RPB; ++r) redf[r][t] = dsq[r];
    __syncthreads();
    for (int s = 128; s >= 1; s >>= 1) {
        if (t < s) {
#pragma unroll
            for (int r = 0; r < RPB; ++r) redf[r][t] += redf[r][t + s];
        }
        __syncthreads();
    }
    if (t < RPB) {
        float v = redf[t][0];
        out1[n0 + t] = v;
        out2[n0 + t] = v;
    }
}

// Kernel 2: entropy of code-usage histogram.
__global__ __launch_bounds__(256) void vq_entropy(const int* __restrict__ hist,
                                                  float* __restrict__ out_ent,
                                                  int n_rows) {
    __shared__ float sdata[256];
    int t = threadIdx.x;
    float local = 0.0f;
    float invn = 1.0f / (float)n_rows;
    for (int k = t; k < NK; k += 256) {
        int h = hist[k];
        if (h > 0) {
            float p = (float)h * invn;   // n_rows = 32768 (pow2) -> exact
            local += p * logf(p);
        }
    }
    sdata[t] = local;
    __syncthreads();
    for (int s = 128; s >= 1; s >>= 1) {
        if (t < s) sdata[t] += sdata[t + s];
        __syncthreads();
    }
    if (t == 0) *out_ent = -sdata[0];
}

extern "C" void kernel_launch(void* const* d_in, const int* in_sizes, int n_in,
                              void* d_out, int out_size, void* d_ws, size_t ws_size,
                              hipStream_t stream) {
    const float* x   = (const float*)d_in[0];   // (B,T,1,256) fp32
    const float* emb = (const float*)d_in[1];   // (1,512,256) fp32

    const int n_rows = in_sizes[0] / NV;        // B*T*C = 32768

    float* out0 = (float*)d_out;                      // N*256
    float* out1 = out0 + (size_t)n_rows * NV;         // N
    float* out2 = out1 + n_rows;                      // N
    float* ent  = out2 + n_rows;                      // 1

    float* esq  = (float*)d_ws;                       // 512 floats
    int*   hist = (int*)((char*)d_ws + NK * sizeof(float)); // 512 ints

    vq_prep<<<(NK + 255) / 256, 256, 0, stream>>>(emb, esq, hist);
    vq_main<<<n_rows / RPB, 256, 0, stream>>>(x, emb, esq, hist, out0, out1, out2);
    vq_entropy<<<1, 256, 0, stream>>>(hist, ent, n_rows);
}

// Round 2
// 116.916 us; speedup vs baseline: 2.3272x; 2.3272x over previous
//
#include <hip/hip_runtime.h>
#include <math.h>

// Problem constants: B*T = 32768 rows, C=1, V=256, K=512 codes.
#define NV 256        // vector dim
#define NK 512        // codebook size
#define BM 128        // rows per block (4 waves * 32)
#define WM 32         // rows per wave (2 M-tiles of 16)

typedef unsigned long long ull;
using short8  = __attribute__((ext_vector_type(8))) short;
using floatx4 = __attribute__((ext_vector_type(4))) float;

// Monotone float -> uint mapping (order-preserving; no NaNs in this problem).
__device__ __forceinline__ unsigned int fkey(float f) {
    unsigned int u = __float_as_uint(f);
    return (u & 0x80000000u) ? ~u : (u | 0x80000000u);
}
// fp32 -> bf16 round-to-nearest-even, pure bit ops.
__device__ __forceinline__ unsigned short f2bf(float f) {
    unsigned int u = __float_as_uint(f);
    u += 0x7fffu + ((u >> 16) & 1u);
    return (unsigned short)(u >> 16);
}
__device__ __forceinline__ float bf2f(unsigned short h) {
    return __uint_as_float(((unsigned int)h) << 16);
}
__device__ __forceinline__ ull shfl_xor64(ull v, int m) {
    unsigned int lo = (unsigned int)(v & 0xffffffffull);
    unsigned int hi = (unsigned int)(v >> 32);
    lo = (unsigned int)__shfl_xor((int)lo, m, 64);
    hi = (unsigned int)__shfl_xor((int)hi, m, 64);
    return ((ull)hi << 32) | (ull)lo;
}

// Kernel 0: per-code squared norm (fp32) + zero histogram.
__global__ __launch_bounds__(256) void vq_prep(const float* __restrict__ emb,
                                               float* __restrict__ esq,
                                               int* __restrict__ hist) {
    int k = blockIdx.x * 256 + threadIdx.x;
    if (k < NK) {
        const float4* e = (const float4*)(emb + (size_t)k * NV);
        float s = 0.0f;
#pragma unroll 8
        for (int v = 0; v < NV / 4; ++v) {
            float4 a = e[v];
            s += a.x * a.x + a.y * a.y + a.z * a.z + a.w * a.w;
        }
        esq[k] = s;
        hist[k] = 0;
    }
}

// Kernel 1: split embedding into bf16 hi/lo planes (elementwise).
__global__ __launch_bounds__(256) void vq_cvt(const float* __restrict__ emb,
                                              unsigned short* __restrict__ eh,
                                              unsigned short* __restrict__ el) {
    int i = (blockIdx.x * 256 + threadIdx.x) * 4;
    float4 v = *(const float4*)(emb + i);
    ushort4 h, l;
    h.x = f2bf(v.x); l.x = f2bf(v.x - bf2f(h.x));
    h.y = f2bf(v.y); l.y = f2bf(v.y - bf2f(h.y));
    h.z = f2bf(v.z); l.z = f2bf(v.z - bf2f(h.z));
    h.w = f2bf(v.w); l.w = f2bf(v.w - bf2f(h.w));
    *(ushort4*)(eh + i) = h;
    *(ushort4*)(el + i) = l;
}

// B-fragment load for one 16-code tile (hi+lo planes), 16B per lane per kstep.
#define LOADB(BH, BL, NT) do {                                          \
    const size_t cb = ((size_t)((NT) * 16 + lr)) * NV + (size_t)lg * 8; \
    _Pragma("unroll")                                                   \
    for (int ks = 0; ks < 8; ++ks) {                                    \
        BH[ks] = *(const short8*)(eh + cb + ks * 32);                   \
        BL[ks] = *(const short8*)(el + cb + ks * 32);                   \
    }                                                                   \
} while (0)

// 3-pass split MFMA for one 16-code tile + fused argmin update.
#define COMPUTE(BH, BL, NT) do {                                                     \
    floatx4 acc0 = {0.f, 0.f, 0.f, 0.f};                                             \
    floatx4 acc1 = {0.f, 0.f, 0.f, 0.f};                                             \
    _Pragma("unroll")                                                                \
    for (int ks = 0; ks < 8; ++ks) {                                                 \
        acc0 = __builtin_amdgcn_mfma_f32_16x16x32_bf16(ah[0][ks], BH[ks], acc0, 0, 0, 0); \
        acc0 = __builtin_amdgcn_mfma_f32_16x16x32_bf16(al[0][ks], BH[ks], acc0, 0, 0, 0); \
        acc0 = __builtin_amdgcn_mfma_f32_16x16x32_bf16(ah[0][ks], BL[ks], acc0, 0, 0, 0); \
        acc1 = __builtin_amdgcn_mfma_f32_16x16x32_bf16(ah[1][ks], BH[ks], acc1, 0, 0, 0); \
        acc1 = __builtin_amdgcn_mfma_f32_16x16x32_bf16(al[1][ks], BH[ks], acc1, 0, 0, 0); \
        acc1 = __builtin_amdgcn_mfma_f32_16x16x32_bf16(ah[1][ks], BL[ks], acc1, 0, 0, 0); \
    }                                                                                \
    const float evq = esq[(NT) * 16 + lr];                                           \
    const unsigned int code = (unsigned int)((NT) * 16 + lr);                        \
    _Pragma("unroll")                                                                \
    for (int j = 0; j < 4; ++j) {                                                    \
        ull k0 = ((ull)fkey(fmaf(-2.0f, acc0[j], evq)) << 32) | code;                \
        ull k1 = ((ull)fkey(fmaf(-2.0f, acc1[j], evq)) << 32) | code;                \
        if (k0 < rmin0[j]) rmin0[j] = k0;                                            \
        if (k1 < rmin1[j]) rmin1[j] = k1;                                            \
    }                                                                                \
} while (0)

// Kernel 2: MFMA nearest-code search + gather/ST output + loss sums.
// 4 waves/block, each wave owns 32 rows; streams all 512 codes from L2.
__global__ __launch_bounds__(256) void vq_main(
    const float* __restrict__ x,
    const float* __restrict__ emb,
    const unsigned short* __restrict__ eh,
    const unsigned short* __restrict__ el,
    const float* __restrict__ esq,
    int* __restrict__ hist,
    float* __restrict__ out0,
    float* __restrict__ out1,
    float* __restrict__ out2) {
    __shared__ int idx_lds[BM];

    const int t = threadIdx.x;
    const int wid = t >> 6;
    const int lane = t & 63;
    const int lr = lane & 15;   // row (A) / code (B) within tile
    const int lg = lane >> 4;   // k-slice group
    const size_t n0w = (size_t)blockIdx.x * BM + (size_t)wid * WM;

    // ---- A fragments: 32 rows of x -> bf16 hi/lo in registers ----
    short8 ah[2][8], al[2][8];
#pragma unroll
    for (int mt = 0; mt < 2; ++mt) {
#pragma unroll
        for (int ks = 0; ks < 8; ++ks) {
            const float* p = x + (n0w + mt * 16 + lr) * NV + ks * 32 + lg * 8;
            float4 u0 = *(const float4*)p;
            float4 u1 = *(const float4*)(p + 4);
            float f[8] = {u0.x, u0.y, u0.z, u0.w, u1.x, u1.y, u1.z, u1.w};
            short8 h, l;
#pragma unroll
            for (int j = 0; j < 8; ++j) {
                unsigned short hb = f2bf(f[j]);
                h[j] = (short)hb;
                l[j] = (short)f2bf(f[j] - bf2f(hb));
            }
            ah[mt][ks] = h;
            al[mt][ks] = l;
        }
    }

    ull rmin0[4], rmin1[4];
#pragma unroll
    for (int j = 0; j < 4; ++j) { rmin0[j] = ~0ull; rmin1[j] = ~0ull; }

    // ---- main loop over 32 code tiles, register-double-buffered B ----
    short8 bh0[8], bl0[8], bh1[8], bl1[8];
    LOADB(bh0, bl0, 0);
#pragma unroll 1
    for (int nt = 0; nt < 32; nt += 2) {
        LOADB(bh1, bl1, nt + 1);
        COMPUTE(bh0, bl0, nt);
        if (nt + 2 < 32) LOADB(bh0, bl0, nt + 2);
        COMPUTE(bh1, bl1, nt + 1);
    }

    // ---- reduce argmin across the 16 code-lanes (low 4 lane bits) ----
#pragma unroll
    for (int j = 0; j < 4; ++j) {
#pragma unroll
        for (int m = 1; m <= 8; m <<= 1) {
            ull v0 = shfl_xor64(rmin0[j], m);
            ull v1 = shfl_xor64(rmin1[j], m);
            if (v0 < rmin0[j]) rmin0[j] = v0;
            if (v1 < rmin1[j]) rmin1[j] = v1;
        }
    }
    // writer lanes (lr==0): publish idx + histogram
    if (lr == 0) {
#pragma unroll
        for (int j = 0; j < 4; ++j) {
            int i0 = (int)(rmin0[j] & 0xffffffffull);
            int i1 = (int)(rmin1[j] & 0xffffffffull);
            idx_lds[wid * WM + lg * 4 + j] = i0;
            idx_lds[wid * WM + 16 + lg * 4 + j] = i1;
            atomicAdd(&hist[i0], 1);
            atomicAdd(&hist[i1], 1);
        }
    }
    __syncthreads();

    // ---- epilogue: gather e[idx], straight-through out0, loss sums ----
    for (int rr = 0; rr < WM; ++rr) {
        const size_t row = n0w + rr;
        const int idx = idx_lds[wid * WM + rr];
        const float4 xv = *(const float4*)(x + row * NV + lane * 4);
        const float4 ev = *(const float4*)(emb + (size_t)idx * NV + lane * 4);
        float4 o;
        o.x = (ev.x - xv.x) + xv.x;
        o.y = (ev.y - xv.y) + xv.y;
        o.z = (ev.z - xv.z) + xv.z;
        o.w = (ev.w - xv.w) + xv.w;
        *(float4*)(out0 + row * NV + lane * 4) = o;
        float d0 = xv.x - ev.x, d1 = xv.y - ev.y, d2 = xv.z - ev.z, d3 = xv.w - ev.w;
        float s = d0 * d0 + d1 * d1 + d2 * d2 + d3 * d3;
#pragma unroll
        for (int m = 32; m >= 1; m >>= 1) s += __shfl_xor(s, m, 64);
        if (lane == 0) { out1[row] = s; out2[row] = s; }
    }
}

// Kernel 3: entropy of code-usage histogram.
__global__ __launch_bounds__(256) void vq_entropy(const int* __restrict__ hist,
                                                  float* __restrict__ out_ent,
                                                  int n_rows) {
    __shared__ float sdata[256];
    int t = threadIdx.x;
    float local = 0.0f;
    float invn = 1.0f / (float)n_rows;
    for (int k = t; k < NK; k += 256) {
        int h = hist[k];
        if (h > 0) {
            float p = (float)h * invn;
            local += p * logf(p);
        }
    }
    sdata[t] = local;
    __syncthreads();
    for (int s = 128; s >= 1; s >>= 1) {
        if (t < s) sdata[t] += sdata[t + s];
        __syncthreads();
    }
    if (t == 0) *out_ent = -sdata[0];
}

extern "C" void kernel_launch(void* const* d_in, const int* in_sizes, int n_in,
                              void* d_out, int out_size, void* d_ws, size_t ws_size,
                              hipStream_t stream) {
    const float* x   = (const float*)d_in[0];   // (B,T,1,256) fp32
    const float* emb = (const float*)d_in[1];   // (1,512,256) fp32

    const int n_rows = in_sizes[0] / NV;        // 32768

    float* out0 = (float*)d_out;
    float* out1 = out0 + (size_t)n_rows * NV;
    float* out2 = out1 + n_rows;
    float* ent  = out2 + n_rows;

    // workspace: esq (2KB) | hist (2KB) | e_hi (256KB) | e_lo (256KB)
    float* esq = (float*)d_ws;
    int* hist  = (int*)(esq + NK);
    unsigned short* eh = (unsigned short*)(hist + NK);
    unsigned short* el = eh + (size_t)NK * NV;

    vq_prep<<<2, 256, 0, stream>>>(emb, esq, hist);
    vq_cvt<<<(NK * NV / 4) / 256, 256, 0, stream>>>(emb, eh, el);
    vq_main<<<n_rows / BM, 256, 0, stream>>>(x, emb, eh, el, esq, hist,
                                             out0, out1, out2);
    vq_entropy<<<1, 256, 0, stream>>>(hist, ent, n_rows);
}

// Round 3
// 86.196 us; speedup vs baseline: 3.1565x; 1.3564x over previous
//
#include <hip/hip_runtime.h>
#include <math.h>

// Problem constants: B*T = 32768 rows, C=1, V=256, K=512 codes.
#define NV 256
#define NK 512
#define BM 128        // rows per block = 4 waves * 32
#define WM 32         // rows per wave (2 M-tiles of 16)
#define TSH 8192      // shorts per staged code-tile (2 planes * 16 codes * 256 dims)

typedef unsigned long long ull;
typedef unsigned short u16;
using short8  = __attribute__((ext_vector_type(8))) short;
using floatx4 = __attribute__((ext_vector_type(4))) float;

// Monotone float -> uint mapping (order-preserving; no NaNs in this problem).
__device__ __forceinline__ unsigned int fkey(float f) {
    unsigned int u = __float_as_uint(f);
    return (u & 0x80000000u) ? ~u : (u | 0x80000000u);
}
// fp32 -> bf16 round-to-nearest-even.
__device__ __forceinline__ u16 f2bf(float f) {
    unsigned int u = __float_as_uint(f);
    u += 0x7fffu + ((u >> 16) & 1u);
    return (u16)(u >> 16);
}
__device__ __forceinline__ float bf2f(u16 h) {
    return __uint_as_float(((unsigned int)h) << 16);
}
__device__ __forceinline__ ull shfl_xor64(ull v, int m) {
    unsigned int lo = (unsigned int)(v & 0xffffffffull);
    unsigned int hi = (unsigned int)(v >> 32);
    lo = (unsigned int)__shfl_xor((int)lo, m, 64);
    hi = (unsigned int)__shfl_xor((int)hi, m, 64);
    return ((ull)hi << 32) | (ull)lo;
}
__device__ __forceinline__ floatx4 mfma16(short8 a, short8 b, floatx4 c) {
    return __builtin_amdgcn_mfma_f32_16x16x32_bf16(a, b, c, 0, 0, 0);
}
// async global -> LDS, 16B per lane. LDS dest = uniform base + lane*16.
__device__ __forceinline__ void gload_lds16(const u16* g, u16* l) {
    __builtin_amdgcn_global_load_lds(
        (const __attribute__((address_space(1))) void*)g,
        (__attribute__((address_space(3))) void*)l, 16, 0, 0);
}

// Kernel 0 (fused prep+cvt): per-code esq, bf16 hi/lo split packed into the
// MFMA-consumption-order tile layout: shorts[tile][plane][kc][code][8],
// so vq_main's ds_read address is exactly lane*16 (conflict-free, linear).
__global__ __launch_bounds__(256) void vq_prepcvt(const float* __restrict__ emb,
                                                  float* __restrict__ esq,
                                                  u16* __restrict__ ehws,
                                                  int* __restrict__ hist) {
    const int t = threadIdx.x;
    const int lane = t & 63;
    const int code = blockIdx.x * 4 + (t >> 6);   // one wave per code
    const int nt = code >> 4, c = code & 15;
    const float4 v = *(const float4*)(emb + (size_t)code * NV + lane * 4);
    ushort4 h, l;
    h.x = f2bf(v.x); l.x = f2bf(v.x - bf2f(h.x));
    h.y = f2bf(v.y); l.y = f2bf(v.y - bf2f(h.y));
    h.z = f2bf(v.z); l.z = f2bf(v.z - bf2f(h.z));
    h.w = f2bf(v.w); l.w = f2bf(v.w - bf2f(h.w));
    // dim base = lane*4 -> kchunk = lane>>1, j0 = (lane&1)*4
    const size_t base = (size_t)nt * TSH + (size_t)(lane >> 1) * 128 + c * 8 + (lane & 1) * 4;
    *(ushort4*)(ehws + base)        = h;
    *(ushort4*)(ehws + base + 4096) = l;
    float s = v.x * v.x + v.y * v.y + v.z * v.z + v.w * v.w;
#pragma unroll
    for (int m = 1; m <= 32; m <<= 1) s += __shfl_xor(s, m, 64);
    if (lane == 0) esq[code] = s;
    const int g = blockIdx.x * 256 + t;
    if (g < NK) hist[g] = 0;
}

// Kernel 1: MFMA nearest-code search + outputs.
// 4 waves/block, 32 rows/wave, grid=256 (1 block/CU). Latency hidden by a
// 4-buffer LDS pipeline: stage 3 tiles ahead via global_load_lds, counted
// vmcnt(12), raw s_barrier (no vmcnt drain).
__global__ __launch_bounds__(256, 1) void vq_main(
    const float* __restrict__ x,
    const float* __restrict__ emb,
    const u16* __restrict__ ehws,
    const float* __restrict__ esq,
    int* __restrict__ hist,
    float* __restrict__ out0,
    float* __restrict__ out1,
    float* __restrict__ out2) {
    __shared__ u16 lds_b[4 * TSH];        // 64 KB
    __shared__ float esq_lds[NK];
    __shared__ int idx_lds[BM];

    const int t = threadIdx.x;
    const int wid = t >> 6;
    const int lane = t & 63;
    const int lr = lane & 15;
    const int lg = lane >> 4;
    const size_t n0w = (size_t)blockIdx.x * BM + (size_t)wid * WM;

#define STAGE(B, NT) do {                                                   \
        const u16* gs = ehws + (size_t)(NT) * TSH + wid * 2048 + lane * 8;  \
        u16* lb = &lds_b[(B) * TSH + wid * 2048];                           \
        gload_lds16(gs,        lb);                                         \
        gload_lds16(gs +  512, lb +  512);                                  \
        gload_lds16(gs + 1024, lb + 1024);                                  \
        gload_lds16(gs + 1536, lb + 1536);                                  \
    } while (0)

    // ---- prologue: issue first 3 tile-stages, then A-frags under that latency ----
    STAGE(0, 0);
    STAGE(1, 1);
    STAGE(2, 2);

    esq_lds[t] = esq[t];
    esq_lds[t + 256] = esq[t + 256];

    short8 ah[2][8], al[2][8];
#pragma unroll
    for (int mt = 0; mt < 2; ++mt) {
#pragma unroll
        for (int ks = 0; ks < 8; ++ks) {
            const float* p = x + (n0w + mt * 16 + lr) * NV + ks * 32 + lg * 8;
            float4 u0 = *(const float4*)p;
            float4 u1 = *(const float4*)(p + 4);
            float f[8] = {u0.x, u0.y, u0.z, u0.w, u1.x, u1.y, u1.z, u1.w};
            short8 h, l;
#pragma unroll
            for (int j = 0; j < 8; ++j) {
                u16 hb = f2bf(f[j]);
                h[j] = (short)hb;
                l[j] = (short)f2bf(f[j] - bf2f(hb));
            }
            ah[mt][ks] = h;
            al[mt][ks] = l;
        }
    }

    ull rmin0[4], rmin1[4];
#pragma unroll
    for (int j = 0; j < 4; ++j) { rmin0[j] = ~0ull; rmin1[j] = ~0ull; }

    // ---- main loop: 32 code tiles ----
#pragma unroll 4
    for (int nt = 0; nt < 32; ++nt) {
        const int b = nt & 3;
        // all waves finished reading the buffer we are about to overwrite
        asm volatile("s_waitcnt lgkmcnt(0)" ::: "memory");
        __builtin_amdgcn_s_barrier();
        asm volatile("" ::: "memory");
        STAGE((nt + 3) & 3, (nt + 3 < 32) ? (nt + 3) : 31);  // dummy-clamp keeps vmcnt uniform
        asm volatile("s_waitcnt vmcnt(12)" ::: "memory");     // tile nt fully landed (this wave's share)
        __builtin_amdgcn_s_barrier();                         // ... and every other wave's share
        asm volatile("" ::: "memory");

        const u16* bb = &lds_b[b * TSH + lane * 8];
        floatx4 hh0 = {0.f,0.f,0.f,0.f}, lh0 = {0.f,0.f,0.f,0.f}, hl0 = {0.f,0.f,0.f,0.f};
        floatx4 hh1 = {0.f,0.f,0.f,0.f}, lh1 = {0.f,0.f,0.f,0.f}, hl1 = {0.f,0.f,0.f,0.f};
#pragma unroll
        for (int ks = 0; ks < 8; ++ks) {
            short8 bh = *(const short8*)(bb + ks * 512);
            short8 bl = *(const short8*)(bb + ks * 512 + 4096);
            hh0 = mfma16(ah[0][ks], bh, hh0);
            lh0 = mfma16(al[0][ks], bh, lh0);
            hl0 = mfma16(ah[0][ks], bl, hl0);
            hh1 = mfma16(ah[1][ks], bh, hh1);
            lh1 = mfma16(al[1][ks], bh, lh1);
            hl1 = mfma16(ah[1][ks], bl, hl1);
        }
        const float evq = esq_lds[nt * 16 + lr];
        const unsigned int code = (unsigned int)(nt * 16 + lr);
#pragma unroll
        for (int j = 0; j < 4; ++j) {
            float d0 = fmaf(-2.0f, (hh0[j] + lh0[j]) + hl0[j], evq);
            float d1 = fmaf(-2.0f, (hh1[j] + lh1[j]) + hl1[j], evq);
            ull k0 = ((ull)fkey(d0) << 32) | code;
            ull k1 = ((ull)fkey(d1) << 32) | code;
            if (k0 < rmin0[j]) rmin0[j] = k0;
            if (k1 < rmin1[j]) rmin1[j] = k1;
        }
    }
#undef STAGE

    // ---- argmin across the 16 code-lanes ----
#pragma unroll
    for (int j = 0; j < 4; ++j) {
#pragma unroll
        for (int m = 1; m <= 8; m <<= 1) {
            ull v0 = shfl_xor64(rmin0[j], m);
            ull v1 = shfl_xor64(rmin1[j], m);
            if (v0 < rmin0[j]) rmin0[j] = v0;
            if (v1 < rmin1[j]) rmin1[j] = v1;
        }
    }
    if (lr == 0) {
#pragma unroll
        for (int j = 0; j < 4; ++j) {
            int i0 = (int)(rmin0[j] & 0xffffffffull);
            int i1 = (int)(rmin1[j] & 0xffffffffull);
            idx_lds[wid * WM + lg * 4 + j]      = i0;
            idx_lds[wid * WM + 16 + lg * 4 + j] = i1;
            atomicAdd(&hist[i0], 1);
            atomicAdd(&hist[i1], 1);
        }
    }
    __syncthreads();

    // ---- epilogue: gather e[idx]; x' reconstructed from resident A-frags ----
    const int idx0 = idx_lds[wid * WM + lr];
    const int idx1 = idx_lds[wid * WM + 16 + lr];
    float s0 = 0.0f, s1 = 0.0f;
#pragma unroll
    for (int ks = 0; ks < 8; ++ks) {
#pragma unroll
        for (int mt = 0; mt < 2; ++mt) {
            const int idx = mt ? idx1 : idx0;
            const float* ep = emb + (size_t)idx * NV + ks * 32 + lg * 8;
            float4 e0 = *(const float4*)ep;
            float4 e1 = *(const float4*)(ep + 4);
            float ee[8] = {e0.x, e0.y, e0.z, e0.w, e1.x, e1.y, e1.z, e1.w};
            float ov[8];
            float ssum = 0.0f;
#pragma unroll
            for (int j = 0; j < 8; ++j) {
                float xv = bf2f((u16)ah[mt][ks][j]) + bf2f((u16)al[mt][ks][j]);
                ov[j] = (ee[j] - xv) + xv;
                float d = xv - ee[j];
                ssum += d * d;
            }
            float* dst = out0 + (n0w + mt * 16 + lr) * NV + ks * 32 + lg * 8;
            *(float4*)dst       = *(float4*)&ov[0];
            *(float4*)(dst + 4) = *(float4*)&ov[4];
            if (mt) s1 += ssum; else s0 += ssum;
        }
    }
    s0 += __shfl_xor(s0, 16, 64); s0 += __shfl_xor(s0, 32, 64);
    s1 += __shfl_xor(s1, 16, 64); s1 += __shfl_xor(s1, 32, 64);
    if (lg == 0) {
        out1[n0w + lr] = s0;      out2[n0w + lr] = s0;
        out1[n0w + 16 + lr] = s1; out2[n0w + 16 + lr] = s1;
    }
}

// Kernel 2: entropy of code-usage histogram.
__global__ __launch_bounds__(256) void vq_entropy(const int* __restrict__ hist,
                                                  float* __restrict__ out_ent,
                                                  int n_rows) {
    __shared__ float sdata[256];
    int t = threadIdx.x;
    float local = 0.0f;
    float invn = 1.0f / (float)n_rows;
    for (int k = t; k < NK; k += 256) {
        int h = hist[k];
        if (h > 0) {
            float p = (float)h * invn;
            local += p * logf(p);
        }
    }
    sdata[t] = local;
    __syncthreads();
    for (int s = 128; s >= 1; s >>= 1) {
        if (t < s) sdata[t] += sdata[t + s];
        __syncthreads();
    }
    if (t == 0) *out_ent = -sdata[0];
}

extern "C" void kernel_launch(void* const* d_in, const int* in_sizes, int n_in,
                              void* d_out, int out_size, void* d_ws, size_t ws_size,
                              hipStream_t stream) {
    const float* x   = (const float*)d_in[0];   // (B,T,1,256) fp32
    const float* emb = (const float*)d_in[1];   // (1,512,256) fp32

    const int n_rows = in_sizes[0] / NV;        // 32768

    float* out0 = (float*)d_out;
    float* out1 = out0 + (size_t)n_rows * NV;
    float* out2 = out1 + n_rows;
    float* ent  = out2 + n_rows;

    // workspace: esq (2KB) | hist (2KB) | packed bf16 hi/lo tiles (512KB)
    float* esq = (float*)d_ws;
    int* hist  = (int*)(esq + NK);
    u16* ehws  = (u16*)(hist + NK);

    vq_prepcvt<<<NK / 4, 256, 0, stream>>>(emb, esq, ehws, hist);
    vq_main<<<n_rows / BM, 256, 0, stream>>>(x, emb, ehws, esq, hist,
                                             out0, out1, out2);
    vq_entropy<<<1, 256, 0, stream>>>(hist, ent, n_rows);
}

// Round 4
// 70.745 us; speedup vs baseline: 3.8459x; 1.2184x over previous
//
#include <hip/hip_runtime.h>
#include <math.h>

// Problem constants: B*T = 32768 rows, C=1, V=256, K=512 codes.
#define NV 256
#define NK 512
#define BM 64         // rows per block = 4 waves * 16
#define WM 16         // rows per wave (1 M-tile)
#define TSH 8192      // shorts per staged code-tile (2 planes * 16 codes * 256 dims)

typedef unsigned long long ull;
typedef unsigned short u16;
using short8  = __attribute__((ext_vector_type(8))) short;
using floatx4 = __attribute__((ext_vector_type(4))) float;

// Monotone float -> uint mapping (order-preserving; no NaNs in this problem).
__device__ __forceinline__ unsigned int fkey(float f) {
    unsigned int u = __float_as_uint(f);
    return (u & 0x80000000u) ? ~u : (u | 0x80000000u);
}
// fp32 -> bf16 round-to-nearest-even.
__device__ __forceinline__ u16 f2bf(float f) {
    unsigned int u = __float_as_uint(f);
    u += 0x7fffu + ((u >> 16) & 1u);
    return (u16)(u >> 16);
}
__device__ __forceinline__ float bf2f(u16 h) {
    return __uint_as_float(((unsigned int)h) << 16);
}
__device__ __forceinline__ ull shfl_xor64(ull v, int m) {
    unsigned int lo = (unsigned int)(v & 0xffffffffull);
    unsigned int hi = (unsigned int)(v >> 32);
    lo = (unsigned int)__shfl_xor((int)lo, m, 64);
    hi = (unsigned int)__shfl_xor((int)hi, m, 64);
    return ((ull)hi << 32) | (ull)lo;
}
__device__ __forceinline__ floatx4 mfma16(short8 a, short8 b, floatx4 c) {
    return __builtin_amdgcn_mfma_f32_16x16x32_bf16(a, b, c, 0, 0, 0);
}
// async global -> LDS, 16B per lane. LDS dest = uniform base + lane*16.
__device__ __forceinline__ void gload_lds16(const u16* g, u16* l) {
    __builtin_amdgcn_global_load_lds(
        (const __attribute__((address_space(1))) void*)g,
        (__attribute__((address_space(3))) void*)l, 16, 0, 0);
}

// Kernel 0 (fused prep+cvt): per-code esq, bf16 hi/lo split packed into the
// MFMA-consumption-order tile layout: shorts[tile][plane][kc][code][8],
// so vq_main's ds_read address is exactly lane*16 (conflict-free, linear).
__global__ __launch_bounds__(256) void vq_prepcvt(const float* __restrict__ emb,
                                                  float* __restrict__ esq,
                                                  u16* __restrict__ ehws,
                                                  int* __restrict__ hist) {
    const int t = threadIdx.x;
    const int lane = t & 63;
    const int code = blockIdx.x * 4 + (t >> 6);   // one wave per code
    const int nt = code >> 4, c = code & 15;
    const float4 v = *(const float4*)(emb + (size_t)code * NV + lane * 4);
    ushort4 h, l;
    h.x = f2bf(v.x); l.x = f2bf(v.x - bf2f(h.x));
    h.y = f2bf(v.y); l.y = f2bf(v.y - bf2f(h.y));
    h.z = f2bf(v.z); l.z = f2bf(v.z - bf2f(h.z));
    h.w = f2bf(v.w); l.w = f2bf(v.w - bf2f(h.w));
    // dim base = lane*4 -> kchunk = lane>>1, j0 = (lane&1)*4
    const size_t base = (size_t)nt * TSH + (size_t)(lane >> 1) * 128 + c * 8 + (lane & 1) * 4;
    *(ushort4*)(ehws + base)        = h;
    *(ushort4*)(ehws + base + 4096) = l;
    float s = v.x * v.x + v.y * v.y + v.z * v.z + v.w * v.w;
#pragma unroll
    for (int m = 1; m <= 32; m <<= 1) s += __shfl_xor(s, m, 64);
    if (lane == 0) esq[code] = s;
    const int g = blockIdx.x * 256 + t;
    if (g < NK) hist[g] = 0;
}

// Kernel 1: MFMA nearest-code search + outputs.
// 4 waves/block, 16 rows/wave, grid=512 (2 blocks/CU -> 2 waves/SIMD).
// 4-buffer LDS pipeline: stage 3 tiles ahead via global_load_lds, counted
// vmcnt(12), raw s_barrier (no vmcnt drain).
__global__ __launch_bounds__(256, 2) void vq_main(
    const float* __restrict__ x,
    const float* __restrict__ emb,
    const u16* __restrict__ ehws,
    const float* __restrict__ esq,
    int* __restrict__ hist,
    float* __restrict__ out0,
    float* __restrict__ out1,
    float* __restrict__ out2) {
    __shared__ u16 lds_b[4 * TSH];        // 64 KB
    __shared__ float esq_lds[NK];
    __shared__ int idx_lds[BM];

    const int t = threadIdx.x;
    const int wid = t >> 6;
    const int lane = t & 63;
    const int lr = lane & 15;
    const int lg = lane >> 4;
    const size_t n0w = (size_t)blockIdx.x * BM + (size_t)wid * WM;

#define STAGE(B, NT) do {                                                   \
        const u16* gs = ehws + (size_t)(NT) * TSH + wid * 2048 + lane * 8;  \
        u16* lb = &lds_b[(B) * TSH + wid * 2048];                           \
        gload_lds16(gs,        lb);                                         \
        gload_lds16(gs +  512, lb +  512);                                  \
        gload_lds16(gs + 1024, lb + 1024);                                  \
        gload_lds16(gs + 1536, lb + 1536);                                  \
    } while (0)

    // ---- prologue: issue first 3 tile-stages, then A-frags under that latency ----
    STAGE(0, 0);
    STAGE(1, 1);
    STAGE(2, 2);

    esq_lds[t] = esq[t];
    esq_lds[t + 256] = esq[t + 256];

    // ---- A fragments: 16 rows of x -> bf16 hi/lo in registers ----
    short8 ah[8], al[8];
#pragma unroll
    for (int ks = 0; ks < 8; ++ks) {
        const float* p = x + (n0w + lr) * NV + ks * 32 + lg * 8;
        float4 u0 = *(const float4*)p;
        float4 u1 = *(const float4*)(p + 4);
        float f[8] = {u0.x, u0.y, u0.z, u0.w, u1.x, u1.y, u1.z, u1.w};
        short8 h, l;
#pragma unroll
        for (int j = 0; j < 8; ++j) {
            u16 hb = f2bf(f[j]);
            h[j] = (short)hb;
            l[j] = (short)f2bf(f[j] - bf2f(hb));
        }
        ah[ks] = h;
        al[ks] = l;
    }

    ull rmin[4];
#pragma unroll
    for (int j = 0; j < 4; ++j) rmin[j] = ~0ull;

    // ---- main loop: 32 code tiles ----
#pragma unroll 4
    for (int nt = 0; nt < 32; ++nt) {
        const int b = nt & 3;
        // all waves finished reading the buffer we are about to overwrite
        asm volatile("s_waitcnt lgkmcnt(0)" ::: "memory");
        __builtin_amdgcn_s_barrier();
        asm volatile("" ::: "memory");
        STAGE((nt + 3) & 3, (nt + 3 < 32) ? (nt + 3) : 31);  // dummy-clamp keeps vmcnt uniform
        asm volatile("s_waitcnt vmcnt(12)" ::: "memory");     // tile nt fully landed (this wave's share)
        __builtin_amdgcn_s_barrier();                         // ... and every other wave's share
        asm volatile("" ::: "memory");

        const u16* bb = &lds_b[b * TSH + lane * 8];
        floatx4 hh = {0.f,0.f,0.f,0.f}, lh = {0.f,0.f,0.f,0.f}, hl = {0.f,0.f,0.f,0.f};
#pragma unroll
        for (int ks = 0; ks < 8; ++ks) {
            short8 bh = *(const short8*)(bb + ks * 512);
            short8 bl = *(const short8*)(bb + ks * 512 + 4096);
            hh = mfma16(ah[ks], bh, hh);
            lh = mfma16(al[ks], bh, lh);
            hl = mfma16(ah[ks], bl, hl);
        }
        const float evq = esq_lds[nt * 16 + lr];
        const unsigned int code = (unsigned int)(nt * 16 + lr);
#pragma unroll
        for (int j = 0; j < 4; ++j) {
            float d = fmaf(-2.0f, (hh[j] + lh[j]) + hl[j], evq);
            ull k = ((ull)fkey(d) << 32) | code;
            if (k < rmin[j]) rmin[j] = k;
        }
    }
#undef STAGE

    // ---- argmin across the 16 code-lanes ----
#pragma unroll
    for (int j = 0; j < 4; ++j) {
#pragma unroll
        for (int m = 1; m <= 8; m <<= 1) {
            ull v = shfl_xor64(rmin[j], m);
            if (v < rmin[j]) rmin[j] = v;
        }
    }
    if (lr == 0) {
#pragma unroll
        for (int j = 0; j < 4; ++j) {
            int i0 = (int)(rmin[j] & 0xffffffffull);
            idx_lds[wid * WM + lg * 4 + j] = i0;
            atomicAdd(&hist[i0], 1);
        }
    }
    __syncthreads();

    // ---- epilogue: gather e[idx]; x' reconstructed from resident A-frags ----
    const int idx = idx_lds[wid * WM + lr];
    float s0 = 0.0f;
#pragma unroll
    for (int ks = 0; ks < 8; ++ks) {
        const float* ep = emb + (size_t)idx * NV + ks * 32 + lg * 8;
        float4 e0 = *(const float4*)ep;
        float4 e1 = *(const float4*)(ep + 4);
        float ee[8] = {e0.x, e0.y, e0.z, e0.w, e1.x, e1.y, e1.z, e1.w};
        float ov[8];
#pragma unroll
        for (int j = 0; j < 8; ++j) {
            float xv = bf2f((u16)ah[ks][j]) + bf2f((u16)al[ks][j]);
            ov[j] = (ee[j] - xv) + xv;
            float d = xv - ee[j];
            s0 += d * d;
        }
        float* dst = out0 + (n0w + lr) * NV + ks * 32 + lg * 8;
        *(float4*)dst       = *(float4*)&ov[0];
        *(float4*)(dst + 4) = *(float4*)&ov[4];
    }
    s0 += __shfl_xor(s0, 16, 64);
    s0 += __shfl_xor(s0, 32, 64);
    if (lg == 0) {
        out1[n0w + lr] = s0;
        out2[n0w + lr] = s0;
    }
}

// Kernel 2: entropy of code-usage histogram.
__global__ __launch_bounds__(256) void vq_entropy(const int* __restrict__ hist,
                                                  float* __restrict__ out_ent,
                                                  int n_rows) {
    __shared__ float sdata[256];
    int t = threadIdx.x;
    float local = 0.0f;
    float invn = 1.0f / (float)n_rows;
    for (int k = t; k < NK; k += 256) {
        int h = hist[k];
        if (h > 0) {
            float p = (float)h * invn;
            local += p * logf(p);
        }
    }
    sdata[t] = local;
    __syncthreads();
    for (int s = 128; s >= 1; s >>= 1) {
        if (t < s) sdata[t] += sdata[t + s];
        __syncthreads();
    }
    if (t == 0) *out_ent = -sdata[0];
}

extern "C" void kernel_launch(void* const* d_in, const int* in_sizes, int n_in,
                              void* d_out, int out_size, void* d_ws, size_t ws_size,
                              hipStream_t stream) {
    const float* x   = (const float*)d_in[0];   // (B,T,1,256) fp32
    const float* emb = (const float*)d_in[1];   // (1,512,256) fp32

    const int n_rows = in_sizes[0] / NV;        // 32768

    float* out0 = (float*)d_out;
    float* out1 = out0 + (size_t)n_rows * NV;
    float* out2 = out1 + n_rows;
    float* ent  = out2 + n_rows;

    // workspace: esq (2KB) | hist (2KB) | packed bf16 hi/lo tiles (512KB)
    float* esq = (float*)d_ws;
    int* hist  = (int*)(esq + NK);
    u16* ehws  = (u16*)(hist + NK);

    vq_prepcvt<<<NK / 4, 256, 0, stream>>>(emb, esq, ehws, hist);
    vq_main<<<n_rows / BM, 256, 0, stream>>>(x, emb, ehws, esq, hist,
                                             out0, out1, out2);
    vq_entropy<<<1, 256, 0, stream>>>(hist, ent, n_rows);
}

// Round 5
// 67.033 us; speedup vs baseline: 4.0589x; 1.0554x over previous
//
#include <hip/hip_runtime.h>
#include <math.h>

// Problem constants: B*T = 32768 rows, C=1, V=256, K=512 codes.
#define NV 256
#define NK 512
#define BM 64         // rows per block = 4 waves * 16
#define WM 16         // rows per wave (1 M-tile)
#define TSH 8192      // shorts per code-tile (2 planes * 16 codes * 256 dims)
#define TGSH 16384    // shorts per granule (2 tiles)
#define NPH 16        // phases (granules)

typedef unsigned long long ull;
typedef unsigned short u16;
using short8  = __attribute__((ext_vector_type(8))) short;
using floatx4 = __attribute__((ext_vector_type(4))) float;

// Monotone float -> uint mapping (order-preserving; no NaNs in this problem).
__device__ __forceinline__ unsigned int fkey(float f) {
    unsigned int u = __float_as_uint(f);
    return (u & 0x80000000u) ? ~u : (u | 0x80000000u);
}
// fp32 -> bf16 round-to-nearest-even.
__device__ __forceinline__ u16 f2bf(float f) {
    unsigned int u = __float_as_uint(f);
    u += 0x7fffu + ((u >> 16) & 1u);
    return (u16)(u >> 16);
}
__device__ __forceinline__ float bf2f(u16 h) {
    return __uint_as_float(((unsigned int)h) << 16);
}
__device__ __forceinline__ ull shfl_xor64(ull v, int m) {
    unsigned int lo = (unsigned int)(v & 0xffffffffull);
    unsigned int hi = (unsigned int)(v >> 32);
    lo = (unsigned int)__shfl_xor((int)lo, m, 64);
    hi = (unsigned int)__shfl_xor((int)hi, m, 64);
    return ((ull)hi << 32) | (ull)lo;
}
__device__ __forceinline__ floatx4 mfma16(short8 a, short8 b, floatx4 c) {
    return __builtin_amdgcn_mfma_f32_16x16x32_bf16(a, b, c, 0, 0, 0);
}
// async global -> LDS, 16B per lane. LDS dest = uniform base + lane*16.
__device__ __forceinline__ void gload_lds16(const u16* g, u16* l) {
    __builtin_amdgcn_global_load_lds(
        (const __attribute__((address_space(1))) void*)g,
        (__attribute__((address_space(3))) void*)l, 16, 0, 0);
}

// Kernel 0 (fused prep+cvt): per-code esq, bf16 hi/lo split packed into the
// MFMA-consumption-order tile layout: shorts[tile][plane][kc][code][8],
// so vq_main's ds_read address is exactly lane*16 (conflict-free, linear).
__global__ __launch_bounds__(256) void vq_prepcvt(const float* __restrict__ emb,
                                                  float* __restrict__ esq,
                                                  u16* __restrict__ ehws,
                                                  int* __restrict__ hist) {
    const int t = threadIdx.x;
    const int lane = t & 63;
    const int code = blockIdx.x * 4 + (t >> 6);   // one wave per code
    const int nt = code >> 4, c = code & 15;
    const float4 v = *(const float4*)(emb + (size_t)code * NV + lane * 4);
    ushort4 h, l;
    h.x = f2bf(v.x); l.x = f2bf(v.x - bf2f(h.x));
    h.y = f2bf(v.y); l.y = f2bf(v.y - bf2f(h.y));
    h.z = f2bf(v.z); l.z = f2bf(v.z - bf2f(h.z));
    h.w = f2bf(v.w); l.w = f2bf(v.w - bf2f(h.w));
    // dim base = lane*4 -> kchunk = lane>>1, j0 = (lane&1)*4
    const size_t base = (size_t)nt * TSH + (size_t)(lane >> 1) * 128 + c * 8 + (lane & 1) * 4;
    *(ushort4*)(ehws + base)        = h;
    *(ushort4*)(ehws + base + 4096) = l;
    float s = v.x * v.x + v.y * v.y + v.z * v.z + v.w * v.w;
#pragma unroll
    for (int m = 1; m <= 32; m <<= 1) s += __shfl_xor(s, m, 64);
    if (lane == 0) esq[code] = s;
    const int g = blockIdx.x * 256 + t;
    if (g < NK) hist[g] = 0;
}

// Kernel 1: MFMA nearest-code search + outputs.
// 4 waves/block, 16 rows/wave, grid=512 (2 blocks/CU -> 2 waves/SIMD).
// 16 phases of 2 code-tiles each; double-buffered 32KB granules staged via
// global_load_lds, counted vmcnt(8), raw s_barrier (never drains vmcnt).
__global__ __launch_bounds__(256, 2) void vq_main(
    const float* __restrict__ x,
    const float* __restrict__ emb,
    const u16* __restrict__ ehws,
    const float* __restrict__ esq,
    int* __restrict__ hist,
    float* __restrict__ out0,
    float* __restrict__ out1,
    float* __restrict__ out2) {
    __shared__ u16 lds_b[2 * TGSH];       // 64 KB
    __shared__ float esq_lds[NK];
    __shared__ int idx_lds[BM];

    const int t = threadIdx.x;
    const int wid = t >> 6;
    const int lane = t & 63;
    const int lr = lane & 15;
    const int lg = lane >> 4;
    const size_t n0w = (size_t)blockIdx.x * BM + (size_t)wid * WM;

    // Stage one 32KB granule (2 tiles): 8 loads/wave, wave slice = 4096 shorts.
#define STAGE(B, P) do {                                                    \
        const u16* gs = ehws + (size_t)(P) * TGSH + wid * 4096 + lane * 8;  \
        u16* lb = &lds_b[(B) * TGSH + wid * 4096];                          \
        gload_lds16(gs,        lb);                                         \
        gload_lds16(gs +  512, lb +  512);                                  \
        gload_lds16(gs + 1024, lb + 1024);                                  \
        gload_lds16(gs + 1536, lb + 1536);                                  \
        gload_lds16(gs + 2048, lb + 2048);                                  \
        gload_lds16(gs + 2560, lb + 2560);                                  \
        gload_lds16(gs + 3072, lb + 3072);                                  \
        gload_lds16(gs + 3584, lb + 3584);                                  \
    } while (0)

    // ---- prologue: issue granule 0, then esq + A-frags under that latency ----
    STAGE(0, 0);

    esq_lds[t] = esq[t];
    esq_lds[t + 256] = esq[t + 256];

    // ---- A fragments: 16 rows of x -> bf16 hi/lo in registers ----
    short8 ah[8], al[8];
#pragma unroll
    for (int ks = 0; ks < 8; ++ks) {
        const float* p = x + (n0w + lr) * NV + ks * 32 + lg * 8;
        float4 u0 = *(const float4*)p;
        float4 u1 = *(const float4*)(p + 4);
        float f[8] = {u0.x, u0.y, u0.z, u0.w, u1.x, u1.y, u1.z, u1.w};
        short8 h, l;
#pragma unroll
        for (int j = 0; j < 8; ++j) {
            u16 hb = f2bf(f[j]);
            h[j] = (short)hb;
            l[j] = (short)f2bf(f[j] - bf2f(hb));
        }
        ah[ks] = h;
        al[ks] = l;
    }

    ull rmin[4];
#pragma unroll
    for (int j = 0; j < 4; ++j) rmin[j] = ~0ull;

    // ---- main loop: 16 phases x 2 code-tiles ----
#pragma unroll 2
    for (int p = 0; p < NPH; ++p) {
        // prefetch next granule (dummy-clamp keeps vmcnt count uniform;
        // the re-staged buffer at p=15 is never read)
        const int pn = (p + 1 < NPH) ? (p + 1) : (NPH - 1);
        STAGE((p + 1) & 1, pn);
        // granule p fully landed for this wave (8 of 16 outstanding remain);
        // lgkmcnt(0) also covers prologue esq ds_write visibility at p==0
        asm volatile("s_waitcnt vmcnt(8) lgkmcnt(0)" ::: "memory");
        __builtin_amdgcn_s_barrier();     // ...and for every other wave's share
        asm volatile("" ::: "memory");

        const u16* gb = &lds_b[(p & 1) * TGSH];
        __builtin_amdgcn_s_setprio(1);
#pragma unroll
        for (int tt = 0; tt < 2; ++tt) {
            const int nt = 2 * p + tt;
            const u16* bb = gb + tt * TSH + lane * 8;
            floatx4 hh = {0.f,0.f,0.f,0.f}, lh = {0.f,0.f,0.f,0.f}, hl = {0.f,0.f,0.f,0.f};
#pragma unroll
            for (int ks = 0; ks < 8; ++ks) {
                short8 bh = *(const short8*)(bb + ks * 512);
                short8 bl = *(const short8*)(bb + ks * 512 + 4096);
                hh = mfma16(ah[ks], bh, hh);
                lh = mfma16(al[ks], bh, lh);
                hl = mfma16(ah[ks], bl, hl);
            }
            const float evq = esq_lds[nt * 16 + lr];
            const unsigned int code = (unsigned int)(nt * 16 + lr);
#pragma unroll
            for (int j = 0; j < 4; ++j) {
                float d = fmaf(-2.0f, (hh[j] + lh[j]) + hl[j], evq);
                ull k = ((ull)fkey(d) << 32) | code;
                if (k < rmin[j]) rmin[j] = k;
            }
        }
        __builtin_amdgcn_s_setprio(0);

        // all waves finished reading this buffer before next phase overwrites it
        asm volatile("s_waitcnt lgkmcnt(0)" ::: "memory");
        __builtin_amdgcn_s_barrier();
        asm volatile("" ::: "memory");
    }
#undef STAGE

    // ---- argmin across the 16 code-lanes ----
#pragma unroll
    for (int j = 0; j < 4; ++j) {
#pragma unroll
        for (int m = 1; m <= 8; m <<= 1) {
            ull v = shfl_xor64(rmin[j], m);
            if (v < rmin[j]) rmin[j] = v;
        }
    }
    if (lr == 0) {
#pragma unroll
        for (int j = 0; j < 4; ++j) {
            int i0 = (int)(rmin[j] & 0xffffffffull);
            idx_lds[wid * WM + lg * 4 + j] = i0;
            atomicAdd(&hist[i0], 1);
        }
    }
    __syncthreads();

    // ---- epilogue: gather e[idx]; x' reconstructed from resident A-frags ----
    const int idx = idx_lds[wid * WM + lr];
    float s0 = 0.0f;
#pragma unroll
    for (int ks = 0; ks < 8; ++ks) {
        const float* ep = emb + (size_t)idx * NV + ks * 32 + lg * 8;
        float4 e0 = *(const float4*)ep;
        float4 e1 = *(const float4*)(ep + 4);
        float ee[8] = {e0.x, e0.y, e0.z, e0.w, e1.x, e1.y, e1.z, e1.w};
        float ov[8];
#pragma unroll
        for (int j = 0; j < 8; ++j) {
            float xv = bf2f((u16)ah[ks][j]) + bf2f((u16)al[ks][j]);
            ov[j] = (ee[j] - xv) + xv;
            float d = xv - ee[j];
            s0 += d * d;
        }
        float* dst = out0 + (n0w + lr) * NV + ks * 32 + lg * 8;
        *(float4*)dst       = *(float4*)&ov[0];
        *(float4*)(dst + 4) = *(float4*)&ov[4];
    }
    s0 += __shfl_xor(s0, 16, 64);
    s0 += __shfl_xor(s0, 32, 64);
    if (lg == 0) {
        out1[n0w + lr] = s0;
        out2[n0w + lr] = s0;
    }
}

// Kernel 2: entropy of code-usage histogram.
__global__ __launch_bounds__(256) void vq_entropy(const int* __restrict__ hist,
                                                  float* __restrict__ out_ent,
                                                  int n_rows) {
    __shared__ float sdata[256];
    int t = threadIdx.x;
    float local = 0.0f;
    float invn = 1.0f / (float)n_rows;
    for (int k = t; k < NK; k += 256) {
        int h = hist[k];
        if (h > 0) {
            float p = (float)h * invn;
            local += p * logf(p);
        }
    }
    sdata[t] = local;
    __syncthreads();
    for (int s = 128; s >= 1; s >>= 1) {
        if (t < s) sdata[t] += sdata[t + s];
        __syncthreads();
    }
    if (t == 0) *out_ent = -sdata[0];
}

extern "C" void kernel_launch(void* const* d_in, const int* in_sizes, int n_in,
                              void* d_out, int out_size, void* d_ws, size_t ws_size,
                              hipStream_t stream) {
    const float* x   = (const float*)d_in[0];   // (B,T,1,256) fp32
    const float* emb = (const float*)d_in[1];   // (1,512,256) fp32

    const int n_rows = in_sizes[0] / NV;        // 32768

    float* out0 = (float*)d_out;
    float* out1 = out0 + (size_t)n_rows * NV;
    float* out2 = out1 + n_rows;
    float* ent  = out2 + n_rows;

    // workspace: esq (2KB) | hist (2KB) | packed bf16 hi/lo tiles (512KB)
    float* esq = (float*)d_ws;
    int* hist  = (int*)(esq + NK);
    u16* ehws  = (u16*)(hist + NK);

    vq_prepcvt<<<NK / 4, 256, 0, stream>>>(emb, esq, ehws, hist);
    vq_main<<<n_rows / BM, 256, 0, stream>>>(x, emb, ehws, esq, hist,
                                             out0, out1, out2);
    vq_entropy<<<1, 256, 0, stream>>>(hist, ent, n_rows);
}

// Round 6
// 52.769 us; speedup vs baseline: 5.1561x; 1.2703x over previous
//
#include <hip/hip_runtime.h>
#include <math.h>

// Problem constants: B*T = 32768 rows, C=1, V=256, K=512 codes.
#define NV 256
#define NK 512
#define BM 64         // rows per block = 4 waves * 16
#define WM 16         // rows per wave (1 M-tile)
#define TSH 4096      // shorts per code-tile (single bf16 plane: 16 codes * 256 dims)
#define TGSH 16384    // shorts per granule (4 tiles)
#define NPH 8         // phases (granules)

typedef unsigned long long ull;
typedef unsigned short u16;
typedef unsigned int u32;
using short8  = __attribute__((ext_vector_type(8))) short;
using floatx4 = __attribute__((ext_vector_type(4))) float;

// fp32 -> bf16 round-to-nearest-even.
__device__ __forceinline__ u16 f2bf(float f) {
    unsigned int u = __float_as_uint(f);
    u += 0x7fffu + ((u >> 16) & 1u);
    return (u16)(u >> 16);
}
__device__ __forceinline__ float bf2f(u16 h) {
    return __uint_as_float(((unsigned int)h) << 16);
}
__device__ __forceinline__ floatx4 mfma16(short8 a, short8 b, floatx4 c) {
    return __builtin_amdgcn_mfma_f32_16x16x32_bf16(a, b, c, 0, 0, 0);
}
// async global -> LDS, 16B per lane. LDS dest = uniform base + lane*16.
__device__ __forceinline__ void gload_lds16(const u16* g, u16* l) {
    __builtin_amdgcn_global_load_lds(
        (const __attribute__((address_space(1))) void*)g,
        (__attribute__((address_space(3))) void*)l, 16, 0, 0);
}

// Kernel 0 (fused prep+cvt): per-code esq(+2.0 bias for positive-key argmin),
// bf16 codebook packed in MFMA-consumption order: shorts[tile][kc][code][8],
// so vq_main's ds_read address is exactly lane*16 (conflict-free, linear).
__global__ __launch_bounds__(256) void vq_prepcvt(const float* __restrict__ emb,
                                                  float* __restrict__ esq1,
                                                  u16* __restrict__ ehws,
                                                  int* __restrict__ hist) {
    const int t = threadIdx.x;
    const int lane = t & 63;
    const int code = blockIdx.x * 4 + (t >> 6);   // one wave per code
    const int nt = code >> 4, c = code & 15;
    const float4 v = *(const float4*)(emb + (size_t)code * NV + lane * 4);
    ushort4 h;
    h.x = f2bf(v.x);
    h.y = f2bf(v.y);
    h.z = f2bf(v.z);
    h.w = f2bf(v.w);
    // dim base = lane*4 -> kchunk8 = lane>>1, j0 = (lane&1)*4
    const size_t base = (size_t)nt * TSH + (size_t)(lane >> 1) * 128 + c * 8 + (lane & 1) * 4;
    *(ushort4*)(ehws + base) = h;
    float s = v.x * v.x + v.y * v.y + v.z * v.z + v.w * v.w;
#pragma unroll
    for (int m = 1; m <= 32; m <<= 1) s += __shfl_xor(s, m, 64);
    if (lane == 0) esq1[code] = s + 2.0f;   // +2: keys provably positive
    const int g = blockIdx.x * 256 + t;
    if (g < NK) hist[g] = 0;
}

// Kernel 1: MFMA nearest-code search + outputs.
// 4 waves/block, 16 rows/wave, grid=512 (2 blocks/CU -> 2 waves/SIMD).
// 8 phases of 4 code-tiles; double-buffered 32KB granules staged via
// global_load_lds, counted vmcnt(8), raw s_barrier (never drains vmcnt).
__global__ __launch_bounds__(256, 2) void vq_main(
    const float* __restrict__ x,
    const float* __restrict__ emb,
    const u16* __restrict__ ehws,
    const float* __restrict__ esq1,
    int* __restrict__ hist,
    float* __restrict__ out0,
    float* __restrict__ out1,
    float* __restrict__ out2) {
    __shared__ u16 lds_b[2 * TGSH];       // 64 KB
    __shared__ float esq_lds[NK];
    __shared__ int idx_lds[BM];

    const int t = threadIdx.x;
    const int wid = t >> 6;
    const int lane = t & 63;
    const int lr = lane & 15;
    const int lg = lane >> 4;
    const size_t n0w = (size_t)blockIdx.x * BM + (size_t)wid * WM;

    // Stage one 32KB granule (4 tiles): 8 loads/wave, wave slice = 4096 shorts.
#define STAGE(B, P) do {                                                    \
        const u16* gs = ehws + (size_t)(P) * TGSH + wid * 4096 + lane * 8;  \
        u16* lb = &lds_b[(B) * TGSH + wid * 4096];                          \
        gload_lds16(gs,        lb);                                         \
        gload_lds16(gs +  512, lb +  512);                                  \
        gload_lds16(gs + 1024, lb + 1024);                                  \
        gload_lds16(gs + 1536, lb + 1536);                                  \
        gload_lds16(gs + 2048, lb + 2048);                                  \
        gload_lds16(gs + 2560, lb + 2560);                                  \
        gload_lds16(gs + 3072, lb + 3072);                                  \
        gload_lds16(gs + 3584, lb + 3584);                                  \
    } while (0)

    // ---- prologue: issue granule 0, then esq + A-frags under that latency ----
    STAGE(0, 0);

    esq_lds[t] = esq1[t];
    esq_lds[t + 256] = esq1[t + 256];

    // ---- A fragments: 16 rows of x -> bf16 hi (search) + lo (epilogue only) ----
    short8 ah[8], al[8];
#pragma unroll
    for (int ks = 0; ks < 8; ++ks) {
        const float* p = x + (n0w + lr) * NV + ks * 32 + lg * 8;
        float4 u0 = *(const float4*)p;
        float4 u1 = *(const float4*)(p + 4);
        float f[8] = {u0.x, u0.y, u0.z, u0.w, u1.x, u1.y, u1.z, u1.w};
        short8 h, l;
#pragma unroll
        for (int j = 0; j < 8; ++j) {
            u16 hb = f2bf(f[j]);
            h[j] = (short)hb;
            l[j] = (short)f2bf(f[j] - bf2f(hb));
        }
        ah[ks] = h;
        al[ks] = l;
    }

    u32 rmin[4];
#pragma unroll
    for (int j = 0; j < 4; ++j) rmin[j] = 0xffffffffu;

    // ---- main loop: 8 phases x 4 code-tiles ----
#pragma unroll 2
    for (int p = 0; p < NPH; ++p) {
        // prefetch next granule (dummy-clamp keeps vmcnt count uniform;
        // the re-staged buffer at p=7 is never read)
        const int pn = (p + 1 < NPH) ? (p + 1) : (NPH - 1);
        STAGE((p + 1) & 1, pn);
        // granule p fully landed for this wave (8 outstanding = next granule);
        // lgkmcnt(0) also covers prologue esq ds_write visibility at p==0
        asm volatile("s_waitcnt vmcnt(8) lgkmcnt(0)" ::: "memory");
        __builtin_amdgcn_s_barrier();     // ...and for every other wave's share
        asm volatile("" ::: "memory");

        const u16* gb = &lds_b[(p & 1) * TGSH];
        __builtin_amdgcn_s_setprio(1);
#pragma unroll
        for (int tt = 0; tt < 4; ++tt) {
            const int nt = 4 * p + tt;
            const u16* bb = gb + tt * TSH + lane * 8;
            floatx4 acc = {0.f, 0.f, 0.f, 0.f};
#pragma unroll
            for (int ks = 0; ks < 8; ++ks) {
                short8 bh = *(const short8*)(bb + ks * 512);
                acc = mfma16(ah[ks], bh, acc);
            }
            const float evq = esq_lds[nt * 16 + lr];          // esq + 2.0
            const u32 code = (u32)(nt * 16 + lr);
#pragma unroll
            for (int j = 0; j < 4; ++j) {
                // d+2 = (esq+2) - 2*cross  > 0  -> raw bits are monotone
                float d = fmaf(-2.0f, acc[j], evq);
                u32 key = (__float_as_uint(d) & 0xfffffe00u) | code;
                rmin[j] = min(rmin[j], key);
            }
        }
        __builtin_amdgcn_s_setprio(0);

        // all waves finished reading this buffer before next phase overwrites it
        asm volatile("s_waitcnt lgkmcnt(0)" ::: "memory");
        __builtin_amdgcn_s_barrier();
        asm volatile("" ::: "memory");
    }
#undef STAGE

    // ---- argmin across the 16 code-lanes (32-bit min) ----
#pragma unroll
    for (int j = 0; j < 4; ++j) {
#pragma unroll
        for (int m = 1; m <= 8; m <<= 1) {
            u32 v = (u32)__shfl_xor((int)rmin[j], m, 64);
            rmin[j] = min(rmin[j], v);
        }
    }
    if (lr == 0) {
#pragma unroll
        for (int j = 0; j < 4; ++j) {
            int i0 = (int)(rmin[j] & 511u);
            idx_lds[wid * WM + lg * 4 + j] = i0;
            atomicAdd(&hist[i0], 1);
        }
    }
    __syncthreads();

    // ---- epilogue: gather e[idx]; x' = hi+lo reconstruction (error ~1e-5) ----
    const int idx = idx_lds[wid * WM + lr];
    float s0 = 0.0f;
#pragma unroll
    for (int ks = 0; ks < 8; ++ks) {
        const float* ep = emb + (size_t)idx * NV + ks * 32 + lg * 8;
        float4 e0 = *(const float4*)ep;
        float4 e1 = *(const float4*)(ep + 4);
        float ee[8] = {e0.x, e0.y, e0.z, e0.w, e1.x, e1.y, e1.z, e1.w};
        float ov[8];
#pragma unroll
        for (int j = 0; j < 8; ++j) {
            float xv = bf2f((u16)ah[ks][j]) + bf2f((u16)al[ks][j]);
            ov[j] = (ee[j] - xv) + xv;
            float d = xv - ee[j];
            s0 += d * d;
        }
        float* dst = out0 + (n0w + lr) * NV + ks * 32 + lg * 8;
        *(float4*)dst       = *(float4*)&ov[0];
        *(float4*)(dst + 4) = *(float4*)&ov[4];
    }
    s0 += __shfl_xor(s0, 16, 64);
    s0 += __shfl_xor(s0, 32, 64);
    if (lg == 0) {
        out1[n0w + lr] = s0;
        out2[n0w + lr] = s0;
    }
}

// Kernel 2: entropy of code-usage histogram.
__global__ __launch_bounds__(256) void vq_entropy(const int* __restrict__ hist,
                                                  float* __restrict__ out_ent,
                                                  int n_rows) {
    __shared__ float sdata[256];
    int t = threadIdx.x;
    float local = 0.0f;
    float invn = 1.0f / (float)n_rows;
    for (int k = t; k < NK; k += 256) {
        int h = hist[k];
        if (h > 0) {
            float p = (float)h * invn;
            local += p * logf(p);
        }
    }
    sdata[t] = local;
    __syncthreads();
    for (int s = 128; s >= 1; s >>= 1) {
        if (t < s) sdata[t] += sdata[t + s];
        __syncthreads();
    }
    if (t == 0) *out_ent = -sdata[0];
}

extern "C" void kernel_launch(void* const* d_in, const int* in_sizes, int n_in,
                              void* d_out, int out_size, void* d_ws, size_t ws_size,
                              hipStream_t stream) {
    const float* x   = (const float*)d_in[0];   // (B,T,1,256) fp32
    const float* emb = (const float*)d_in[1];   // (1,512,256) fp32

    const int n_rows = in_sizes[0] / NV;        // 32768

    float* out0 = (float*)d_out;
    float* out1 = out0 + (size_t)n_rows * NV;
    float* out2 = out1 + n_rows;
    float* ent  = out2 + n_rows;

    // workspace: esq+2 (2KB) | hist (2KB) | packed bf16 codebook (256KB)
    float* esq1 = (float*)d_ws;
    int* hist   = (int*)(esq1 + NK);
    u16* ehws   = (u16*)(hist + NK);

    vq_prepcvt<<<NK / 4, 256, 0, stream>>>(emb, esq1, ehws, hist);
    vq_main<<<n_rows / BM, 256, 0, stream>>>(x, emb, ehws, esq1, hist,
                                             out0, out1, out2);
    vq_entropy<<<1, 256, 0, stream>>>(hist, ent, n_rows);
}